// Round 22
// baseline (183.172 us; speedup 1.0000x reference)
//
#include <hip/hip_runtime.h>
#include <stdint.h>

#define N_NODES 50000
#define N_EDGES 800000
#define IN_F    100
#define HID     256
#define NCLS    47
#define K1      224   // 200 padded to 7*32
#define K1S     232   // LDS row stride (bank-spread)
#define K2      256
#define K2S     264
#define NBKT    196   // buckets of 256 dst nodes
#define MASK_WORDS (N_NODES * (HID / 32))   // 400,000

#define MASK_NB ((MASK_WORDS + 255) / 256)            // 1563
#define XCVT_NB ((N_NODES * IN_F / 4 + 255) / 256)    // 4883
#define W1T_NB  ((HID * K1 + 255) / 256)              // 224
#define W2T_NB  ((96 * K2 + 255) / 256)               // 96
#define PREP_NB (MASK_NB + XCVT_NB + W1T_NB + W2T_NB + 1)
#define NODE_NB ((N_NODES + 31) / 32)                 // 1563

typedef __bf16 bf16x8 __attribute__((ext_vector_type(8)));
typedef __bf16 bf16x4 __attribute__((ext_vector_type(4)));
typedef float  f32x4  __attribute__((ext_vector_type(4)));

__device__ __forceinline__ uint32_t rotl32(uint32_t v, uint32_t r) {
    return (v << r) | (v >> (32u - r));
}

// JAX threefry2x32, key=(0,42), partitionable: counter=(0,i), bits=x0^x1.
// bernoulli(0.5) keeps iff MSB==0.  (verified round 2)
__device__ __forceinline__ uint32_t jax_bits(uint32_t i) {
    const uint32_t ks0 = 0u, ks1 = 42u, ks2 = 0x1BD11BDAu ^ 42u;
    uint32_t x0 = 0u + ks0;
    uint32_t x1 = i + ks1;
    x0 += x1; x1 = rotl32(x1, 13); x1 ^= x0;
    x0 += x1; x1 = rotl32(x1, 15); x1 ^= x0;
    x0 += x1; x1 = rotl32(x1, 26); x1 ^= x0;
    x0 += x1; x1 = rotl32(x1,  6); x1 ^= x0;
    x0 += ks1; x1 += ks2 + 1u;
    x0 += x1; x1 = rotl32(x1, 17); x1 ^= x0;
    x0 += x1; x1 = rotl32(x1, 29); x1 ^= x0;
    x0 += x1; x1 = rotl32(x1, 16); x1 ^= x0;
    x0 += x1; x1 = rotl32(x1, 24); x1 ^= x0;
    x0 += ks2; x1 += ks0 + 2u;
    x0 += x1; x1 = rotl32(x1, 13); x1 ^= x0;
    x0 += x1; x1 = rotl32(x1, 15); x1 ^= x0;
    x0 += x1; x1 = rotl32(x1, 26); x1 ^= x0;
    x0 += x1; x1 = rotl32(x1,  6); x1 ^= x0;
    x0 += ks0; x1 += ks1 + 3u;
    x0 += x1; x1 = rotl32(x1, 17); x1 ^= x0;
    x0 += x1; x1 = rotl32(x1, 29); x1 ^= x0;
    x0 += x1; x1 = rotl32(x1, 16); x1 ^= x0;
    x0 += x1; x1 = rotl32(x1, 24); x1 ^= x0;
    x0 += ks1; x1 += ks2 + 4u;
    x0 += x1; x1 = rotl32(x1, 13); x1 ^= x0;
    x0 += x1; x1 = rotl32(x1, 15); x1 ^= x0;
    x0 += x1; x1 = rotl32(x1, 26); x1 ^= x0;
    x0 += x1; x1 = rotl32(x1,  6); x1 ^= x0;
    x0 += ks2; x1 += ks0 + 5u;
    return x0 ^ x1;
}

// ===== merged prep: mask | x->bf16 | W1^T | W2^T | zero gcnt (independent) ===
__global__ __launch_bounds__(256) void prep(
    uint32_t* __restrict__ mask, const float* __restrict__ x,
    __bf16* __restrict__ xb,
    const float* __restrict__ Ws1, const float* __restrict__ Wn1,
    __bf16* __restrict__ w1t,
    const float* __restrict__ Ws2, const float* __restrict__ Wn2,
    __bf16* __restrict__ w2t, int* __restrict__ gcnt)
{
    const int b = blockIdx.x, tid = threadIdx.x;
    if (b < MASK_NB) {
        int w = b * 256 + tid;
        if (w >= MASK_WORDS) return;
        uint32_t base = (uint32_t)w * 32u;
        uint32_t m = 0u;
#pragma unroll
        for (int j = 0; j < 32; ++j) {
            uint32_t bits = jax_bits(base + (uint32_t)j);
            m |= ((~bits) >> 31) << j;
        }
        mask[w] = m;
    } else if (b < MASK_NB + XCVT_NB) {
        int i = (b - MASK_NB) * 256 + tid;
        if (i * 4 >= N_NODES * IN_F) return;
        float4 v = reinterpret_cast<const float4*>(x)[i];
        bf16x4 bb;
        bb[0] = (__bf16)v.x; bb[1] = (__bf16)v.y;
        bb[2] = (__bf16)v.z; bb[3] = (__bf16)v.w;
        *reinterpret_cast<bf16x4*>(xb + i * 4) = bb;
    } else if (b < MASK_NB + XCVT_NB + W1T_NB) {
        int gid = (b - MASK_NB - XCVT_NB) * 256 + tid;
        if (gid >= HID * K1) return;
        int j = gid / K1, k = gid % K1;
        float v = 0.f;
        if (k < IN_F)          v = Ws1[k * HID + j];
        else if (k < 2 * IN_F) v = Wn1[(k - IN_F) * HID + j];
        w1t[gid] = (__bf16)v;
    } else if (b < MASK_NB + XCVT_NB + W1T_NB + W2T_NB) {
        int gid = (b - MASK_NB - XCVT_NB - W1T_NB) * 256 + tid;
        if (gid >= 96 * K2) return;
        int j = gid / K2, k = gid % K2;
        float v = 0.f;
        if (j < NCLS)               v = Ws2[k * NCLS + j];
        else if (j >= 48 && j < 95) v = Wn2[k * NCLS + (j - 48)];
        w2t[gid] = (__bf16)v;
    } else {
        if (tid < NBKT) gcnt[tid] = 0;
    }
}

// ============ locality-partitioned CSR build (dst -> srcs) ===================
__global__ __launch_bounds__(256) void bkt_hist(
    const int* __restrict__ dst, int* __restrict__ gcnt)
{
    __shared__ int lcnt[NBKT];
    for (int t = threadIdx.x; t < NBKT; t += 256) lcnt[t] = 0;
    __syncthreads();
    int base = blockIdx.x * 4096;
    for (int it = 0; it < 16; ++it) {
        int e = base + it * 256 + threadIdx.x;
        if (e < N_EDGES) atomicAdd(&lcnt[dst[e] >> 8], 1);
    }
    __syncthreads();
    for (int t = threadIdx.x; t < NBKT; t += 256)
        if (lcnt[t]) atomicAdd(&gcnt[t], lcnt[t]);
}

__global__ __launch_bounds__(256) void bkt_scan(
    const int* __restrict__ gcnt, int* __restrict__ gbase, int* __restrict__ gcur)
{
    __shared__ int s[256];
    int tid = threadIdx.x;
    int v = (tid < NBKT) ? gcnt[tid] : 0;
    s[tid] = v;
    __syncthreads();
    for (int off = 1; off < 256; off <<= 1) {
        int t = (tid >= off) ? s[tid - off] : 0;
        __syncthreads();
        s[tid] += t;
        __syncthreads();
    }
    if (tid < NBKT) { int ex = s[tid] - v; gbase[tid] = ex; gcur[tid] = ex; }
    if (tid == NBKT - 1) gbase[NBKT] = s[tid];
}

__global__ __launch_bounds__(256) void bkt_bin(
    const int* __restrict__ src, const int* __restrict__ dst,
    int* __restrict__ gcur, uint32_t* __restrict__ ebin)
{
    __shared__ uint32_t ldata[4096];
    __shared__ uint8_t  lbkt[4096];
    __shared__ int lcnt[NBKT], lofs[NBKT], lcur[NBKT], gb[NBKT];
    __shared__ int lscan[256];
    const int tid  = threadIdx.x;
    const int base = blockIdx.x * 4096;

    for (int t = tid; t < NBKT; t += 256) lcnt[t] = 0;
    __syncthreads();

    uint32_t pk[16];
    int bk[16];
    for (int it = 0; it < 16; ++it) {
        int e = base + it * 256 + tid;
        if (e < N_EDGES) {
            int d = dst[e];
            pk[it] = ((uint32_t)d << 16) | (uint32_t)src[e];
            bk[it] = d >> 8;
            atomicAdd(&lcnt[bk[it]], 1);
        } else bk[it] = -1;
    }
    __syncthreads();

    int v = (tid < NBKT) ? lcnt[tid] : 0;
    lscan[tid] = v;
    __syncthreads();
    for (int off = 1; off < 256; off <<= 1) {
        int t = (tid >= off) ? lscan[tid - off] : 0;
        __syncthreads();
        lscan[tid] += t;
        __syncthreads();
    }
    if (tid < NBKT) {
        lofs[tid] = lscan[tid] - v;
        lcur[tid] = 0;
        gb[tid]   = (v > 0) ? atomicAdd(&gcur[tid], v) : 0;
    }
    __syncthreads();

    for (int it = 0; it < 16; ++it) {
        if (bk[it] >= 0) {
            int p = lofs[bk[it]] + atomicAdd(&lcur[bk[it]], 1);
            ldata[p] = pk[it];
            lbkt[p]  = (uint8_t)bk[it];
        }
    }
    __syncthreads();

    const int n = min(4096, N_EDGES - base);
    for (int i = tid; i < n; i += 256) {
        int b = lbkt[i];
        ebin[gb[b] + (i - lofs[b])] = ldata[i];
    }
}

__global__ __launch_bounds__(256) void bkt_build(
    const int* __restrict__ gbase, const uint32_t* __restrict__ ebin,
    int* __restrict__ row_ptr, float* __restrict__ invdeg,
    uint16_t* __restrict__ csr_src)
{
    __shared__ int ldeg[256], lscan[256], lcur[256];
    const int b = blockIdx.x, tid = threadIdx.x;
    const int beg = gbase[b], end = gbase[b + 1], n = end - beg;
    const int node0 = b << 8;
    const int nloc = min(256, N_NODES - node0);

    ldeg[tid] = 0;
    __syncthreads();
    for (int i = tid; i < n; i += 256)
        atomicAdd(&ldeg[(int)(ebin[beg + i] >> 16) - node0], 1);
    __syncthreads();

    int d = ldeg[tid];
    lscan[tid] = d;
    __syncthreads();
    for (int off = 1; off < 256; off <<= 1) {
        int t = (tid >= off) ? lscan[tid - off] : 0;
        __syncthreads();
        lscan[tid] += t;
        __syncthreads();
    }
    int excl = lscan[tid] - d;
    lcur[tid] = excl;
    if (tid < nloc) {
        row_ptr[node0 + tid] = beg + excl;
        invdeg[node0 + tid]  = 1.0f / fmaxf((float)d, 1.0f);
    }
    if (b == NBKT - 1 && tid == 0) row_ptr[N_NODES] = end;
    __syncthreads();

    for (int i = tid; i < n; i += 256) {
        uint32_t pk = ebin[beg + i];
        int ld = (int)(pk >> 16) - node0;
        int pos = atomicAdd(&lcur[ld], 1);
        csr_src[beg + pos] = (uint16_t)(pk & 0xFFFFu);
    }
}

// ====== FUSED agg1 + layer-1 + layer-2: gather-mean -> LDS -> MFMA ===========
// 32 rows/block, 256 thr, 6 blk/CU. 8-edge index window, rows in 2 groups of 4.
__global__ __launch_bounds__(256, 6) void sage_fused(
    const int* __restrict__ row_ptr, const uint16_t* __restrict__ csr_src,
    const __bf16* __restrict__ xb, const float* __restrict__ invdeg,
    const __bf16* __restrict__ w1t, const float* __restrict__ b1,
    const uint32_t* __restrict__ mask,
    const __bf16* __restrict__ w2t, const float* __restrict__ b2,
    float* __restrict__ out, __bf16* __restrict__ z2b)
{
    __shared__ __align__(16) unsigned char smem[32 * K2S * sizeof(__bf16)];
    __bf16 (*xs)[K1S] = reinterpret_cast<__bf16 (*)[K1S]>(smem);
    __bf16 (*hs)[K2S] = reinterpret_cast<__bf16 (*)[K2S]>(smem);
    __shared__ uint32_t msk[32][8];
    const int row0 = blockIdx.x * 32;
    const int tid  = threadIdx.x;
    const int nrow = min(32, N_NODES - row0);

    // ---- step A: own x rows (chunks 0..24) + zero pad (chunks 50..55) ----
    for (int t = tid; t < 32 * 56; t += 256) {
        int r = t / 56, c4 = t % 56;
        if (c4 >= 25 && c4 < 50) continue;   // mean region: step B
        bf16x4 v = {};
        if (r < nrow && c4 < 25)
            v = *reinterpret_cast<const bf16x4*>(xb + (size_t)(row0 + r) * IN_F + c4 * 4);
        *reinterpret_cast<bf16x4*>(&xs[r][c4 * 4]) = v;
    }
    {
        int r = tid >> 3, w8 = tid & 7;
        msk[r][w8] = (r < nrow) ? mask[(size_t)(row0 + r) * 8 + w8] : 0u;
    }

    // ---- step B: gather-mean -> xs[r][100..199]; 8 thr/node, 8-edge window ----
    {
        const int r  = tid >> 3;     // node slot 0..31
        const int j8 = tid & 7;      // chunks {j8, j8+8, j8+16} (+24 if j8==0)
        const int node = row0 + r;
        if (node < N_NODES) {
            f32x4 a0 = {0.f,0.f,0.f,0.f}, a1 = a0, a2 = a0, a3 = a0;
            int beg = row_ptr[node], end = row_ptr[node + 1];
            int e = beg;
            for (; e + 7 < end; e += 8) {
                // prefetch all 8 indices (independent u16 loads in flight)
                int s[8];
#pragma unroll
                for (int u = 0; u < 8; ++u) s[u] = csr_src[e + u];
                // rows in two groups of 4 (12 value-loads in flight each)
#pragma unroll
                for (int g = 0; g < 2; ++g) {
                    const __bf16* xp0 = xb + (size_t)s[g * 4 + 0] * IN_F;
                    const __bf16* xp1 = xb + (size_t)s[g * 4 + 1] * IN_F;
                    const __bf16* xp2 = xb + (size_t)s[g * 4 + 2] * IN_F;
                    const __bf16* xp3 = xb + (size_t)s[g * 4 + 3] * IN_F;
                    bf16x4 p00 = *reinterpret_cast<const bf16x4*>(xp0 + j8 * 4);
                    bf16x4 p01 = *reinterpret_cast<const bf16x4*>(xp0 + (j8 + 8) * 4);
                    bf16x4 p02 = *reinterpret_cast<const bf16x4*>(xp0 + (j8 + 16) * 4);
                    bf16x4 p10 = *reinterpret_cast<const bf16x4*>(xp1 + j8 * 4);
                    bf16x4 p11 = *reinterpret_cast<const bf16x4*>(xp1 + (j8 + 8) * 4);
                    bf16x4 p12 = *reinterpret_cast<const bf16x4*>(xp1 + (j8 + 16) * 4);
                    bf16x4 p20 = *reinterpret_cast<const bf16x4*>(xp2 + j8 * 4);
                    bf16x4 p21 = *reinterpret_cast<const bf16x4*>(xp2 + (j8 + 8) * 4);
                    bf16x4 p22 = *reinterpret_cast<const bf16x4*>(xp2 + (j8 + 16) * 4);
                    bf16x4 p30 = *reinterpret_cast<const bf16x4*>(xp3 + j8 * 4);
                    bf16x4 p31 = *reinterpret_cast<const bf16x4*>(xp3 + (j8 + 8) * 4);
                    bf16x4 p32 = *reinterpret_cast<const bf16x4*>(xp3 + (j8 + 16) * 4);
#pragma unroll
                    for (int q = 0; q < 4; ++q) {
                        a0[q] += ((float)p00[q] + (float)p10[q]) + ((float)p20[q] + (float)p30[q]);
                        a1[q] += ((float)p01[q] + (float)p11[q]) + ((float)p21[q] + (float)p31[q]);
                        a2[q] += ((float)p02[q] + (float)p12[q]) + ((float)p22[q] + (float)p32[q]);
                    }
                    if (j8 == 0) {
                        bf16x4 t0 = *reinterpret_cast<const bf16x4*>(xp0 + 96);
                        bf16x4 t1 = *reinterpret_cast<const bf16x4*>(xp1 + 96);
                        bf16x4 t2 = *reinterpret_cast<const bf16x4*>(xp2 + 96);
                        bf16x4 t3 = *reinterpret_cast<const bf16x4*>(xp3 + 96);
#pragma unroll
                        for (int q = 0; q < 4; ++q)
                            a3[q] += ((float)t0[q] + (float)t1[q]) + ((float)t2[q] + (float)t3[q]);
                    }
                }
            }
            for (; e + 3 < end; e += 4) {
                const __bf16* xp0 = xb + (size_t)csr_src[e]     * IN_F;
                const __bf16* xp1 = xb + (size_t)csr_src[e + 1] * IN_F;
                const __bf16* xp2 = xb + (size_t)csr_src[e + 2] * IN_F;
                const __bf16* xp3 = xb + (size_t)csr_src[e + 3] * IN_F;
                bf16x4 p00 = *reinterpret_cast<const bf16x4*>(xp0 + j8 * 4);
                bf16x4 p01 = *reinterpret_cast<const bf16x4*>(xp0 + (j8 + 8) * 4);
                bf16x4 p02 = *reinterpret_cast<const bf16x4*>(xp0 + (j8 + 16) * 4);
                bf16x4 p10 = *reinterpret_cast<const bf16x4*>(xp1 + j8 * 4);
                bf16x4 p11 = *reinterpret_cast<const bf16x4*>(xp1 + (j8 + 8) * 4);
                bf16x4 p12 = *reinterpret_cast<const bf16x4*>(xp1 + (j8 + 16) * 4);
                bf16x4 p20 = *reinterpret_cast<const bf16x4*>(xp2 + j8 * 4);
                bf16x4 p21 = *reinterpret_cast<const bf16x4*>(xp2 + (j8 + 8) * 4);
                bf16x4 p22 = *reinterpret_cast<const bf16x4*>(xp2 + (j8 + 16) * 4);
                bf16x4 p30 = *reinterpret_cast<const bf16x4*>(xp3 + j8 * 4);
                bf16x4 p31 = *reinterpret_cast<const bf16x4*>(xp3 + (j8 + 8) * 4);
                bf16x4 p32 = *reinterpret_cast<const bf16x4*>(xp3 + (j8 + 16) * 4);
#pragma unroll
                for (int q = 0; q < 4; ++q) {
                    a0[q] += ((float)p00[q] + (float)p10[q]) + ((float)p20[q] + (float)p30[q]);
                    a1[q] += ((float)p01[q] + (float)p11[q]) + ((float)p21[q] + (float)p31[q]);
                    a2[q] += ((float)p02[q] + (float)p12[q]) + ((float)p22[q] + (float)p32[q]);
                }
                if (j8 == 0) {
                    bf16x4 t0 = *reinterpret_cast<const bf16x4*>(xp0 + 96);
                    bf16x4 t1 = *reinterpret_cast<const bf16x4*>(xp1 + 96);
                    bf16x4 t2 = *reinterpret_cast<const bf16x4*>(xp2 + 96);
                    bf16x4 t3 = *reinterpret_cast<const bf16x4*>(xp3 + 96);
#pragma unroll
                    for (int q = 0; q < 4; ++q)
                        a3[q] += ((float)t0[q] + (float)t1[q]) + ((float)t2[q] + (float)t3[q]);
                }
            }
            for (; e < end; ++e) {
                const __bf16* xp = xb + (size_t)csr_src[e] * IN_F;
                bf16x4 p0 = *reinterpret_cast<const bf16x4*>(xp + j8 * 4);
                bf16x4 p1 = *reinterpret_cast<const bf16x4*>(xp + (j8 + 8) * 4);
                bf16x4 p2 = *reinterpret_cast<const bf16x4*>(xp + (j8 + 16) * 4);
#pragma unroll
                for (int q = 0; q < 4; ++q) {
                    a0[q] += (float)p0[q];
                    a1[q] += (float)p1[q];
                    a2[q] += (float)p2[q];
                }
                if (j8 == 0) {
                    bf16x4 p3 = *reinterpret_cast<const bf16x4*>(xp + 96);
#pragma unroll
                    for (int q = 0; q < 4; ++q) a3[q] += (float)p3[q];
                }
            }
            const float inv = invdeg[node];
            bf16x4 r0, r1, r2;
#pragma unroll
            for (int q = 0; q < 4; ++q) {
                r0[q] = (__bf16)(a0[q] * inv);
                r1[q] = (__bf16)(a1[q] * inv);
                r2[q] = (__bf16)(a2[q] * inv);
            }
            *reinterpret_cast<bf16x4*>(&xs[r][IN_F + j8 * 4])        = r0;
            *reinterpret_cast<bf16x4*>(&xs[r][IN_F + (j8 + 8) * 4])  = r1;
            *reinterpret_cast<bf16x4*>(&xs[r][IN_F + (j8 + 16) * 4]) = r2;
            if (j8 == 0) {
                bf16x4 r3;
#pragma unroll
                for (int q = 0; q < 4; ++q) r3[q] = (__bf16)(a3[q] * inv);
                *reinterpret_cast<bf16x4*>(&xs[r][IN_F + 96]) = r3;
            }
        } else {
            bf16x4 z = {};
            *reinterpret_cast<bf16x4*>(&xs[r][IN_F + j8 * 4])        = z;
            *reinterpret_cast<bf16x4*>(&xs[r][IN_F + (j8 + 8) * 4])  = z;
            *reinterpret_cast<bf16x4*>(&xs[r][IN_F + (j8 + 16) * 4]) = z;
            if (j8 == 0) *reinterpret_cast<bf16x4*>(&xs[r][IN_F + 96]) = z;
        }
    }
    __syncthreads();

    const int w    = tid >> 6;          // wave 0..3
    const int lane = tid & 63;
    const int lm   = lane & 15;
    const int hi   = lane >> 4;         // 0..3
    const int lk   = hi * 8;

    // ---- phase 1: h1 = (x||mean) @ W1^T ; wave cols = w*64 + ct*16 + lm ----
    const int wc = w * 64;
    f32x4 acc[4][2];
#pragma unroll
    for (int ct = 0; ct < 4; ++ct)
#pragma unroll
        for (int rg = 0; rg < 2; ++rg) acc[ct][rg] = (f32x4){0.f, 0.f, 0.f, 0.f};

    for (int kk = 0; kk < K1 / 32; ++kk) {
        bf16x8 a[2];
#pragma unroll
        for (int rg = 0; rg < 2; ++rg)
            a[rg] = *reinterpret_cast<const bf16x8*>(&xs[rg * 16 + lm][kk * 32 + lk]);
#pragma unroll
        for (int ct = 0; ct < 4; ++ct) {
            const bf16x8 b = *reinterpret_cast<const bf16x8*>(
                &w1t[(size_t)(wc + ct * 16 + lm) * K1 + kk * 32 + lk]);
#pragma unroll
            for (int rg = 0; rg < 2; ++rg)
                acc[ct][rg] = __builtin_amdgcn_mfma_f32_16x16x32_bf16(a[rg], b, acc[ct][rg], 0, 0, 0);
        }
    }
    __syncthreads();   // all waves done READING xs before hs overwrites it

    // epilogue 1: bias + ReLU + dropout -> hs (LDS)
#pragma unroll
    for (int ct = 0; ct < 4; ++ct) {
        const int col = wc + ct * 16 + lm;
        const float bj = b1[col];
        const int word = (w << 1) + ((ct * 16 + lm) >> 5);
        const int bit  = (ct * 16 + lm) & 31;
#pragma unroll
        for (int rg = 0; rg < 2; ++rg) {
#pragma unroll
            for (int reg = 0; reg < 4; ++reg) {
                int r = rg * 16 + hi * 4 + reg;
                float v = 0.f;
                if (r < nrow) {
                    v = fmaxf(acc[ct][rg][reg] + bj, 0.f);
                    v = ((msk[r][word] >> bit) & 1u) ? v * 2.0f : 0.f;
                }
                hs[r][col] = (__bf16)v;
            }
        }
    }
    __syncthreads();

    // ---- phase 2: [out_self | z2] = h1 @ W2^T ; waves 0..2, 32 cols each ----
    if (w < 3) {
        const int wc2 = w * 32;
        f32x4 acc2[2][2];
#pragma unroll
        for (int ct = 0; ct < 2; ++ct)
#pragma unroll
            for (int rg = 0; rg < 2; ++rg) acc2[ct][rg] = (f32x4){0.f, 0.f, 0.f, 0.f};

        for (int kk = 0; kk < K2 / 32; ++kk) {
            bf16x8 a[2];
#pragma unroll
            for (int rg = 0; rg < 2; ++rg)
                a[rg] = *reinterpret_cast<const bf16x8*>(&hs[rg * 16 + lm][kk * 32 + lk]);
#pragma unroll
            for (int ct = 0; ct < 2; ++ct) {
                const bf16x8 b = *reinterpret_cast<const bf16x8*>(
                    &w2t[(size_t)(wc2 + ct * 16 + lm) * K2 + kk * 32 + lk]);
#pragma unroll
                for (int rg = 0; rg < 2; ++rg)
                    acc2[ct][rg] = __builtin_amdgcn_mfma_f32_16x16x32_bf16(a[rg], b, acc2[ct][rg], 0, 0, 0);
            }
        }

#pragma unroll
        for (int ct = 0; ct < 2; ++ct) {
            const int col = wc2 + ct * 16 + lm;
#pragma unroll
            for (int rg = 0; rg < 2; ++rg) {
#pragma unroll
                for (int reg = 0; reg < 4; ++reg) {
                    int r = rg * 16 + hi * 4 + reg;
                    if (r >= nrow) continue;
                    int g = row0 + r;
                    float v = acc2[ct][rg][reg];
                    if (col < NCLS)                 out[(size_t)g * NCLS + col] = v + b2[col];
                    else if (col >= 48 && col < 95) z2b[(size_t)g * 48 + (col - 48)] = (__bf16)v;
                    else if (col == 95)             z2b[(size_t)g * 48 + 47] = (__bf16)0.f;
                }
            }
        }
    }
}

// ====== pull aggregation, layer 2: bf16 gather x4-unrolled, mean + add =======
__global__ __launch_bounds__(256) void agg2_bf(
    const int* __restrict__ row_ptr, const uint16_t* __restrict__ csr_src,
    const __bf16* __restrict__ z2b, const float* __restrict__ invdeg,
    float* __restrict__ out)
{
    int gid  = blockIdx.x * 256 + threadIdx.x;
    int node = gid >> 4;
    int j    = gid & 15;
    if (node >= N_NODES || j >= 12) return;
    int beg = row_ptr[node], end = row_ptr[node + 1];
    f32x4 acc = {0.f, 0.f, 0.f, 0.f};
    int e = beg;
    for (; e + 3 < end; e += 4) {
        int s0 = csr_src[e],     s1 = csr_src[e + 1];
        int s2 = csr_src[e + 2], s3 = csr_src[e + 3];
        bf16x4 v0 = *reinterpret_cast<const bf16x4*>(z2b + (size_t)s0 * 48 + j * 4);
        bf16x4 v1 = *reinterpret_cast<const bf16x4*>(z2b + (size_t)s1 * 48 + j * 4);
        bf16x4 v2 = *reinterpret_cast<const bf16x4*>(z2b + (size_t)s2 * 48 + j * 4);
        bf16x4 v3 = *reinterpret_cast<const bf16x4*>(z2b + (size_t)s3 * 48 + j * 4);
#pragma unroll
        for (int q = 0; q < 4; ++q)
            acc[q] += ((float)v0[q] + (float)v1[q]) + ((float)v2[q] + (float)v3[q]);
    }
    for (; e < end; ++e) {
        bf16x4 v = *reinterpret_cast<const bf16x4*>(z2b + (size_t)csr_src[e] * 48 + j * 4);
#pragma unroll
        for (int q = 0; q < 4; ++q) acc[q] += (float)v[q];
    }
    float inv = invdeg[node];
#pragma unroll
    for (int q = 0; q < 4; ++q) {
        int col = j * 4 + q;
        if (col < NCLS)
            out[(size_t)node * NCLS + col] += acc[q] * inv;
    }
}

extern "C" void kernel_launch(void* const* d_in, const int* in_sizes, int n_in,
                              void* d_out, int out_size, void* d_ws, size_t ws_size,
                              hipStream_t stream)
{
    const float* x   = (const float*)d_in[0];
    const int*   src = (const int*)  d_in[1];
    const int*   dst = (const int*)  d_in[2];
    const float* Ws1 = (const float*)d_in[3];
    const float* Wn1 = (const float*)d_in[4];
    const float* b1  = (const float*)d_in[5];
    const float* Ws2 = (const float*)d_in[6];
    const float* Wn2 = (const float*)d_in[7];
    const float* b2  = (const float*)d_in[8];
    float* out = (float*)d_out;

    // ---- workspace layout (int-slot / float-slot units) ----
    int*      wsi     = (int*)d_ws;
    int*      row_ptr = wsi;                 //  50,001
    int*      gcnt    = wsi + 50008;         //     196
    int*      gbase   = wsi + 50208;         //     197
    int*      gcur    = wsi + 50408;         //     196
    uint32_t* ebin    = (uint32_t*)(wsi + 50608);    // 800,000 u32
    uint16_t* csr_src = (uint16_t*)(wsi + 850608);   // 800,000 u16
    float*    wsf     = (float*)d_ws;
    float*    invdeg  = wsf + 1300000;               //  50,000 f32
    __bf16*   xb      = (__bf16*)(wsf + 1350000);    //  5.0M bf16
    uint32_t* mask    = (uint32_t*)(wsf + 4250000);  //  400K u32
    __bf16*   w1t     = (__bf16*)(wsf + 4650000);    // 57,344 bf16
    __bf16*   w2t     = (__bf16*)(wsf + 4680000);    // 24,576 bf16
    __bf16*   z2b     = (__bf16*)(wsf + 4700000);    //  2.4M bf16  (~23.6 MB)

    prep<<<PREP_NB, 256, 0, stream>>>(mask, x, xb, Ws1, Wn1, w1t, Ws2, Wn2, w2t, gcnt);

    bkt_hist <<<NBKT, 256, 0, stream>>>(dst, gcnt);
    bkt_scan <<<1, 256, 0, stream>>>(gcnt, gbase, gcur);
    bkt_bin  <<<NBKT, 256, 0, stream>>>(src, dst, gcur, ebin);
    bkt_build<<<NBKT, 256, 0, stream>>>(gbase, ebin, row_ptr, invdeg, csr_src);

    sage_fused<<<NODE_NB, 256, 0, stream>>>(
        row_ptr, csr_src, xb, invdeg, w1t, b1, mask, w2t, b2, out, z2b);
    agg2_bf<<<(N_NODES * 16 + 255) / 256, 256, 0, stream>>>(row_ptr, csr_src, z2b, invdeg, out);
}

// Round 23
// 151.739 us; speedup vs baseline: 1.2072x; 1.2072x over previous
//
#include <hip/hip_runtime.h>
#include <stdint.h>

#define N_NODES 50000
#define N_EDGES 800000
#define IN_F    100
#define HID     256
#define NCLS    47
#define K1      224   // 200 padded to 7*32
#define K1S     232   // LDS row stride (bank-spread)
#define K2      256
#define K2S     264
#define NBKT    196   // buckets of 256 dst nodes
#define MASK_WORDS (N_NODES * (HID / 32))   // 400,000

#define MASK_NB ((MASK_WORDS + 255) / 256)            // 1563
#define XCVT_NB ((N_NODES * IN_F / 4 + 255) / 256)    // 4883
#define W1T_NB  ((HID * K1 + 255) / 256)              // 224
#define W2T_NB  ((96 * K2 + 255) / 256)               // 96
#define PREP_NB (MASK_NB + XCVT_NB + W1T_NB + W2T_NB + 1)
#define NODE_NB ((N_NODES + 31) / 32)                 // 1563

typedef __bf16 bf16x8 __attribute__((ext_vector_type(8)));
typedef __bf16 bf16x4 __attribute__((ext_vector_type(4)));
typedef float  f32x4  __attribute__((ext_vector_type(4)));

__device__ __forceinline__ uint32_t rotl32(uint32_t v, uint32_t r) {
    return (v << r) | (v >> (32u - r));
}

// JAX threefry2x32, key=(0,42), partitionable: counter=(0,i), bits=x0^x1.
// bernoulli(0.5) keeps iff MSB==0.  (verified round 2)
__device__ __forceinline__ uint32_t jax_bits(uint32_t i) {
    const uint32_t ks0 = 0u, ks1 = 42u, ks2 = 0x1BD11BDAu ^ 42u;
    uint32_t x0 = 0u + ks0;
    uint32_t x1 = i + ks1;
    x0 += x1; x1 = rotl32(x1, 13); x1 ^= x0;
    x0 += x1; x1 = rotl32(x1, 15); x1 ^= x0;
    x0 += x1; x1 = rotl32(x1, 26); x1 ^= x0;
    x0 += x1; x1 = rotl32(x1,  6); x1 ^= x0;
    x0 += ks1; x1 += ks2 + 1u;
    x0 += x1; x1 = rotl32(x1, 17); x1 ^= x0;
    x0 += x1; x1 = rotl32(x1, 29); x1 ^= x0;
    x0 += x1; x1 = rotl32(x1, 16); x1 ^= x0;
    x0 += x1; x1 = rotl32(x1, 24); x1 ^= x0;
    x0 += ks2; x1 += ks0 + 2u;
    x0 += x1; x1 = rotl32(x1, 13); x1 ^= x0;
    x0 += x1; x1 = rotl32(x1, 15); x1 ^= x0;
    x0 += x1; x1 = rotl32(x1, 26); x1 ^= x0;
    x0 += x1; x1 = rotl32(x1,  6); x1 ^= x0;
    x0 += ks0; x1 += ks1 + 3u;
    x0 += x1; x1 = rotl32(x1, 17); x1 ^= x0;
    x0 += x1; x1 = rotl32(x1, 29); x1 ^= x0;
    x0 += x1; x1 = rotl32(x1, 16); x1 ^= x0;
    x0 += x1; x1 = rotl32(x1, 24); x1 ^= x0;
    x0 += ks1; x1 += ks2 + 4u;
    x0 += x1; x1 = rotl32(x1, 13); x1 ^= x0;
    x0 += x1; x1 = rotl32(x1, 15); x1 ^= x0;
    x0 += x1; x1 = rotl32(x1, 26); x1 ^= x0;
    x0 += x1; x1 = rotl32(x1,  6); x1 ^= x0;
    x0 += ks2; x1 += ks0 + 5u;
    return x0 ^ x1;
}

// ===== merged prep: mask | x->bf16 | W1^T | W2^T | zero gcnt (independent) ===
__global__ __launch_bounds__(256) void prep(
    uint32_t* __restrict__ mask, const float* __restrict__ x,
    __bf16* __restrict__ xb,
    const float* __restrict__ Ws1, const float* __restrict__ Wn1,
    __bf16* __restrict__ w1t,
    const float* __restrict__ Ws2, const float* __restrict__ Wn2,
    __bf16* __restrict__ w2t, int* __restrict__ gcnt)
{
    const int b = blockIdx.x, tid = threadIdx.x;
    if (b < MASK_NB) {
        int w = b * 256 + tid;
        if (w >= MASK_WORDS) return;
        uint32_t base = (uint32_t)w * 32u;
        uint32_t m = 0u;
#pragma unroll
        for (int j = 0; j < 32; ++j) {
            uint32_t bits = jax_bits(base + (uint32_t)j);
            m |= ((~bits) >> 31) << j;
        }
        mask[w] = m;
    } else if (b < MASK_NB + XCVT_NB) {
        int i = (b - MASK_NB) * 256 + tid;
        if (i * 4 >= N_NODES * IN_F) return;
        float4 v = reinterpret_cast<const float4*>(x)[i];
        bf16x4 bb;
        bb[0] = (__bf16)v.x; bb[1] = (__bf16)v.y;
        bb[2] = (__bf16)v.z; bb[3] = (__bf16)v.w;
        *reinterpret_cast<bf16x4*>(xb + i * 4) = bb;
    } else if (b < MASK_NB + XCVT_NB + W1T_NB) {
        int gid = (b - MASK_NB - XCVT_NB) * 256 + tid;
        if (gid >= HID * K1) return;
        int j = gid / K1, k = gid % K1;
        float v = 0.f;
        if (k < IN_F)          v = Ws1[k * HID + j];
        else if (k < 2 * IN_F) v = Wn1[(k - IN_F) * HID + j];
        w1t[gid] = (__bf16)v;
    } else if (b < MASK_NB + XCVT_NB + W1T_NB + W2T_NB) {
        int gid = (b - MASK_NB - XCVT_NB - W1T_NB) * 256 + tid;
        if (gid >= 96 * K2) return;
        int j = gid / K2, k = gid % K2;
        float v = 0.f;
        if (j < NCLS)               v = Ws2[k * NCLS + j];
        else if (j >= 48 && j < 95) v = Wn2[k * NCLS + (j - 48)];
        w2t[gid] = (__bf16)v;
    } else {
        if (tid < NBKT) gcnt[tid] = 0;
    }
}

// ============ locality-partitioned CSR build (dst -> srcs) ===================
__global__ __launch_bounds__(256) void bkt_hist(
    const int* __restrict__ dst, int* __restrict__ gcnt)
{
    __shared__ int lcnt[NBKT];
    for (int t = threadIdx.x; t < NBKT; t += 256) lcnt[t] = 0;
    __syncthreads();
    int base = blockIdx.x * 4096;
    for (int it = 0; it < 16; ++it) {
        int e = base + it * 256 + threadIdx.x;
        if (e < N_EDGES) atomicAdd(&lcnt[dst[e] >> 8], 1);
    }
    __syncthreads();
    for (int t = threadIdx.x; t < NBKT; t += 256)
        if (lcnt[t]) atomicAdd(&gcnt[t], lcnt[t]);
}

__global__ __launch_bounds__(256) void bkt_scan(
    const int* __restrict__ gcnt, int* __restrict__ gbase, int* __restrict__ gcur)
{
    __shared__ int s[256];
    int tid = threadIdx.x;
    int v = (tid < NBKT) ? gcnt[tid] : 0;
    s[tid] = v;
    __syncthreads();
    for (int off = 1; off < 256; off <<= 1) {
        int t = (tid >= off) ? s[tid - off] : 0;
        __syncthreads();
        s[tid] += t;
        __syncthreads();
    }
    if (tid < NBKT) { int ex = s[tid] - v; gbase[tid] = ex; gcur[tid] = ex; }
    if (tid == NBKT - 1) gbase[NBKT] = s[tid];
}

__global__ __launch_bounds__(256) void bkt_bin(
    const int* __restrict__ src, const int* __restrict__ dst,
    int* __restrict__ gcur, uint32_t* __restrict__ ebin)
{
    __shared__ uint32_t ldata[4096];
    __shared__ uint8_t  lbkt[4096];
    __shared__ int lcnt[NBKT], lofs[NBKT], lcur[NBKT], gb[NBKT];
    __shared__ int lscan[256];
    const int tid  = threadIdx.x;
    const int base = blockIdx.x * 4096;

    for (int t = tid; t < NBKT; t += 256) lcnt[t] = 0;
    __syncthreads();

    uint32_t pk[16];
    int bk[16];
    for (int it = 0; it < 16; ++it) {
        int e = base + it * 256 + tid;
        if (e < N_EDGES) {
            int d = dst[e];
            pk[it] = ((uint32_t)d << 16) | (uint32_t)src[e];
            bk[it] = d >> 8;
            atomicAdd(&lcnt[bk[it]], 1);
        } else bk[it] = -1;
    }
    __syncthreads();

    int v = (tid < NBKT) ? lcnt[tid] : 0;
    lscan[tid] = v;
    __syncthreads();
    for (int off = 1; off < 256; off <<= 1) {
        int t = (tid >= off) ? lscan[tid - off] : 0;
        __syncthreads();
        lscan[tid] += t;
        __syncthreads();
    }
    if (tid < NBKT) {
        lofs[tid] = lscan[tid] - v;
        lcur[tid] = 0;
        gb[tid]   = (v > 0) ? atomicAdd(&gcur[tid], v) : 0;
    }
    __syncthreads();

    for (int it = 0; it < 16; ++it) {
        if (bk[it] >= 0) {
            int p = lofs[bk[it]] + atomicAdd(&lcur[bk[it]], 1);
            ldata[p] = pk[it];
            lbkt[p]  = (uint8_t)bk[it];
        }
    }
    __syncthreads();

    const int n = min(4096, N_EDGES - base);
    for (int i = tid; i < n; i += 256) {
        int b = lbkt[i];
        ebin[gb[b] + (i - lofs[b])] = ldata[i];
    }
}

__global__ __launch_bounds__(256) void bkt_build(
    const int* __restrict__ gbase, const uint32_t* __restrict__ ebin,
    int* __restrict__ row_ptr, float* __restrict__ invdeg,
    uint16_t* __restrict__ csr_src)
{
    __shared__ int ldeg[256], lscan[256], lcur[256];
    const int b = blockIdx.x, tid = threadIdx.x;
    const int beg = gbase[b], end = gbase[b + 1], n = end - beg;
    const int node0 = b << 8;
    const int nloc = min(256, N_NODES - node0);

    ldeg[tid] = 0;
    __syncthreads();
    for (int i = tid; i < n; i += 256)
        atomicAdd(&ldeg[(int)(ebin[beg + i] >> 16) - node0], 1);
    __syncthreads();

    int d = ldeg[tid];
    lscan[tid] = d;
    __syncthreads();
    for (int off = 1; off < 256; off <<= 1) {
        int t = (tid >= off) ? lscan[tid - off] : 0;
        __syncthreads();
        lscan[tid] += t;
        __syncthreads();
    }
    int excl = lscan[tid] - d;
    lcur[tid] = excl;
    if (tid < nloc) {
        row_ptr[node0 + tid] = beg + excl;
        invdeg[node0 + tid]  = 1.0f / fmaxf((float)d, 1.0f);
    }
    if (b == NBKT - 1 && tid == 0) row_ptr[N_NODES] = end;
    __syncthreads();

    for (int i = tid; i < n; i += 256) {
        uint32_t pk = ebin[beg + i];
        int ld = (int)(pk >> 16) - node0;
        int pos = atomicAdd(&lcur[ld], 1);
        csr_src[beg + pos] = (uint16_t)(pk & 0xFFFFu);
    }
}

// ====== FUSED agg1 + layer-1 + layer-2: gather-mean -> LDS -> MFMA ===========
// 32 rows/block, 256 thr, 6 blk/CU. (round-21 structure: x4-unrolled gather)
__global__ __launch_bounds__(256, 6) void sage_fused(
    const int* __restrict__ row_ptr, const uint16_t* __restrict__ csr_src,
    const __bf16* __restrict__ xb, const float* __restrict__ invdeg,
    const __bf16* __restrict__ w1t, const float* __restrict__ b1,
    const uint32_t* __restrict__ mask,
    const __bf16* __restrict__ w2t, const float* __restrict__ b2,
    float* __restrict__ out, __bf16* __restrict__ z2b)
{
    __shared__ __align__(16) unsigned char smem[32 * K2S * sizeof(__bf16)];
    __bf16 (*xs)[K1S] = reinterpret_cast<__bf16 (*)[K1S]>(smem);
    __bf16 (*hs)[K2S] = reinterpret_cast<__bf16 (*)[K2S]>(smem);
    __shared__ uint32_t msk[32][8];
    const int row0 = blockIdx.x * 32;
    const int tid  = threadIdx.x;
    const int nrow = min(32, N_NODES - row0);

    // ---- step A: own x rows (chunks 0..24) + zero pad (chunks 50..55) ----
    for (int t = tid; t < 32 * 56; t += 256) {
        int r = t / 56, c4 = t % 56;
        if (c4 >= 25 && c4 < 50) continue;   // mean region: step B
        bf16x4 v = {};
        if (r < nrow && c4 < 25)
            v = *reinterpret_cast<const bf16x4*>(xb + (size_t)(row0 + r) * IN_F + c4 * 4);
        *reinterpret_cast<bf16x4*>(&xs[r][c4 * 4]) = v;
    }
    {
        int r = tid >> 3, w8 = tid & 7;
        msk[r][w8] = (r < nrow) ? mask[(size_t)(row0 + r) * 8 + w8] : 0u;
    }

    // ---- step B: gather-mean -> xs[r][100..199]; 8 thr/node, x4 edge unroll ----
    {
        const int r  = tid >> 3;     // node slot 0..31
        const int j8 = tid & 7;      // chunks {j8, j8+8, j8+16} (+24 if j8==0)
        const int node = row0 + r;
        if (node < N_NODES) {
            f32x4 a0 = {0.f,0.f,0.f,0.f}, a1 = a0, a2 = a0, a3 = a0;
            int beg = row_ptr[node], end = row_ptr[node + 1];
            int e = beg;
            for (; e + 3 < end; e += 4) {          // 12-16 independent loads
                const __bf16* xp0 = xb + (size_t)csr_src[e]     * IN_F;
                const __bf16* xp1 = xb + (size_t)csr_src[e + 1] * IN_F;
                const __bf16* xp2 = xb + (size_t)csr_src[e + 2] * IN_F;
                const __bf16* xp3 = xb + (size_t)csr_src[e + 3] * IN_F;
                bf16x4 p00 = *reinterpret_cast<const bf16x4*>(xp0 + j8 * 4);
                bf16x4 p01 = *reinterpret_cast<const bf16x4*>(xp0 + (j8 + 8) * 4);
                bf16x4 p02 = *reinterpret_cast<const bf16x4*>(xp0 + (j8 + 16) * 4);
                bf16x4 p10 = *reinterpret_cast<const bf16x4*>(xp1 + j8 * 4);
                bf16x4 p11 = *reinterpret_cast<const bf16x4*>(xp1 + (j8 + 8) * 4);
                bf16x4 p12 = *reinterpret_cast<const bf16x4*>(xp1 + (j8 + 16) * 4);
                bf16x4 p20 = *reinterpret_cast<const bf16x4*>(xp2 + j8 * 4);
                bf16x4 p21 = *reinterpret_cast<const bf16x4*>(xp2 + (j8 + 8) * 4);
                bf16x4 p22 = *reinterpret_cast<const bf16x4*>(xp2 + (j8 + 16) * 4);
                bf16x4 p30 = *reinterpret_cast<const bf16x4*>(xp3 + j8 * 4);
                bf16x4 p31 = *reinterpret_cast<const bf16x4*>(xp3 + (j8 + 8) * 4);
                bf16x4 p32 = *reinterpret_cast<const bf16x4*>(xp3 + (j8 + 16) * 4);
#pragma unroll
                for (int q = 0; q < 4; ++q) {
                    a0[q] += ((float)p00[q] + (float)p10[q]) + ((float)p20[q] + (float)p30[q]);
                    a1[q] += ((float)p01[q] + (float)p11[q]) + ((float)p21[q] + (float)p31[q]);
                    a2[q] += ((float)p02[q] + (float)p12[q]) + ((float)p22[q] + (float)p32[q]);
                }
                if (j8 == 0) {
                    bf16x4 t0 = *reinterpret_cast<const bf16x4*>(xp0 + 96);
                    bf16x4 t1 = *reinterpret_cast<const bf16x4*>(xp1 + 96);
                    bf16x4 t2 = *reinterpret_cast<const bf16x4*>(xp2 + 96);
                    bf16x4 t3 = *reinterpret_cast<const bf16x4*>(xp3 + 96);
#pragma unroll
                    for (int q = 0; q < 4; ++q)
                        a3[q] += ((float)t0[q] + (float)t1[q]) + ((float)t2[q] + (float)t3[q]);
                }
            }
            for (; e < end; ++e) {
                const __bf16* xp = xb + (size_t)csr_src[e] * IN_F;
                bf16x4 p0 = *reinterpret_cast<const bf16x4*>(xp + j8 * 4);
                bf16x4 p1 = *reinterpret_cast<const bf16x4*>(xp + (j8 + 8) * 4);
                bf16x4 p2 = *reinterpret_cast<const bf16x4*>(xp + (j8 + 16) * 4);
#pragma unroll
                for (int q = 0; q < 4; ++q) {
                    a0[q] += (float)p0[q];
                    a1[q] += (float)p1[q];
                    a2[q] += (float)p2[q];
                }
                if (j8 == 0) {
                    bf16x4 p3 = *reinterpret_cast<const bf16x4*>(xp + 96);
#pragma unroll
                    for (int q = 0; q < 4; ++q) a3[q] += (float)p3[q];
                }
            }
            const float inv = invdeg[node];
            bf16x4 r0, r1, r2;
#pragma unroll
            for (int q = 0; q < 4; ++q) {
                r0[q] = (__bf16)(a0[q] * inv);
                r1[q] = (__bf16)(a1[q] * inv);
                r2[q] = (__bf16)(a2[q] * inv);
            }
            *reinterpret_cast<bf16x4*>(&xs[r][IN_F + j8 * 4])        = r0;
            *reinterpret_cast<bf16x4*>(&xs[r][IN_F + (j8 + 8) * 4])  = r1;
            *reinterpret_cast<bf16x4*>(&xs[r][IN_F + (j8 + 16) * 4]) = r2;
            if (j8 == 0) {
                bf16x4 r3;
#pragma unroll
                for (int q = 0; q < 4; ++q) r3[q] = (__bf16)(a3[q] * inv);
                *reinterpret_cast<bf16x4*>(&xs[r][IN_F + 96]) = r3;
            }
        } else {
            bf16x4 z = {};
            *reinterpret_cast<bf16x4*>(&xs[r][IN_F + j8 * 4])        = z;
            *reinterpret_cast<bf16x4*>(&xs[r][IN_F + (j8 + 8) * 4])  = z;
            *reinterpret_cast<bf16x4*>(&xs[r][IN_F + (j8 + 16) * 4]) = z;
            if (j8 == 0) *reinterpret_cast<bf16x4*>(&xs[r][IN_F + 96]) = z;
        }
    }
    __syncthreads();

    const int w    = tid >> 6;          // wave 0..3
    const int lane = tid & 63;
    const int lm   = lane & 15;
    const int hi   = lane >> 4;         // 0..3
    const int lk   = hi * 8;

    // ---- phase 1: h1 = (x||mean) @ W1^T ; wave cols = w*64 + ct*16 + lm ----
    const int wc = w * 64;
    f32x4 acc[4][2];
#pragma unroll
    for (int ct = 0; ct < 4; ++ct)
#pragma unroll
        for (int rg = 0; rg < 2; ++rg) acc[ct][rg] = (f32x4){0.f, 0.f, 0.f, 0.f};

    for (int kk = 0; kk < K1 / 32; ++kk) {
        bf16x8 a[2];
#pragma unroll
        for (int rg = 0; rg < 2; ++rg)
            a[rg] = *reinterpret_cast<const bf16x8*>(&xs[rg * 16 + lm][kk * 32 + lk]);
#pragma unroll
        for (int ct = 0; ct < 4; ++ct) {
            const bf16x8 b = *reinterpret_cast<const bf16x8*>(
                &w1t[(size_t)(wc + ct * 16 + lm) * K1 + kk * 32 + lk]);
#pragma unroll
            for (int rg = 0; rg < 2; ++rg)
                acc[ct][rg] = __builtin_amdgcn_mfma_f32_16x16x32_bf16(a[rg], b, acc[ct][rg], 0, 0, 0);
        }
    }
    __syncthreads();   // all waves done READING xs before hs overwrites it

    // epilogue 1: bias + ReLU + dropout -> hs (LDS)
#pragma unroll
    for (int ct = 0; ct < 4; ++ct) {
        const int col = wc + ct * 16 + lm;
        const float bj = b1[col];
        const int word = (w << 1) + ((ct * 16 + lm) >> 5);
        const int bit  = (ct * 16 + lm) & 31;
#pragma unroll
        for (int rg = 0; rg < 2; ++rg) {
#pragma unroll
            for (int reg = 0; reg < 4; ++reg) {
                int r = rg * 16 + hi * 4 + reg;
                float v = 0.f;
                if (r < nrow) {
                    v = fmaxf(acc[ct][rg][reg] + bj, 0.f);
                    v = ((msk[r][word] >> bit) & 1u) ? v * 2.0f : 0.f;
                }
                hs[r][col] = (__bf16)v;
            }
        }
    }
    __syncthreads();

    // ---- phase 2: [out_self | z2] = h1 @ W2^T ; waves 0..2, 32 cols each ----
    if (w < 3) {
        const int wc2 = w * 32;
        f32x4 acc2[2][2];
#pragma unroll
        for (int ct = 0; ct < 2; ++ct)
#pragma unroll
            for (int rg = 0; rg < 2; ++rg) acc2[ct][rg] = (f32x4){0.f, 0.f, 0.f, 0.f};

        for (int kk = 0; kk < K2 / 32; ++kk) {
            bf16x8 a[2];
#pragma unroll
            for (int rg = 0; rg < 2; ++rg)
                a[rg] = *reinterpret_cast<const bf16x8*>(&hs[rg * 16 + lm][kk * 32 + lk]);
#pragma unroll
            for (int ct = 0; ct < 2; ++ct) {
                const bf16x8 b = *reinterpret_cast<const bf16x8*>(
                    &w2t[(size_t)(wc2 + ct * 16 + lm) * K2 + kk * 32 + lk]);
#pragma unroll
                for (int rg = 0; rg < 2; ++rg)
                    acc2[ct][rg] = __builtin_amdgcn_mfma_f32_16x16x32_bf16(a[rg], b, acc2[ct][rg], 0, 0, 0);
            }
        }

#pragma unroll
        for (int ct = 0; ct < 2; ++ct) {
            const int col = wc2 + ct * 16 + lm;
#pragma unroll
            for (int rg = 0; rg < 2; ++rg) {
#pragma unroll
                for (int reg = 0; reg < 4; ++reg) {
                    int r = rg * 16 + hi * 4 + reg;
                    if (r >= nrow) continue;
                    int g = row0 + r;
                    float v = acc2[ct][rg][reg];
                    if (col < NCLS)                 out[(size_t)g * NCLS + col] = v + b2[col];
                    else if (col >= 48 && col < 95) z2b[(size_t)g * 48 + (col - 48)] = (__bf16)v;
                    else if (col == 95)             z2b[(size_t)g * 48 + 47] = (__bf16)0.f;
                }
            }
        }
    }
}

// ====== pull aggregation, layer 2: bf16 gather x4-unrolled, mean + add =======
__global__ __launch_bounds__(256) void agg2_bf(
    const int* __restrict__ row_ptr, const uint16_t* __restrict__ csr_src,
    const __bf16* __restrict__ z2b, const float* __restrict__ invdeg,
    float* __restrict__ out)
{
    int gid  = blockIdx.x * 256 + threadIdx.x;
    int node = gid >> 4;
    int j    = gid & 15;
    if (node >= N_NODES || j >= 12) return;
    int beg = row_ptr[node], end = row_ptr[node + 1];
    f32x4 acc = {0.f, 0.f, 0.f, 0.f};
    int e = beg;
    for (; e + 3 < end; e += 4) {
        int s0 = csr_src[e],     s1 = csr_src[e + 1];
        int s2 = csr_src[e + 2], s3 = csr_src[e + 3];
        bf16x4 v0 = *reinterpret_cast<const bf16x4*>(z2b + (size_t)s0 * 48 + j * 4);
        bf16x4 v1 = *reinterpret_cast<const bf16x4*>(z2b + (size_t)s1 * 48 + j * 4);
        bf16x4 v2 = *reinterpret_cast<const bf16x4*>(z2b + (size_t)s2 * 48 + j * 4);
        bf16x4 v3 = *reinterpret_cast<const bf16x4*>(z2b + (size_t)s3 * 48 + j * 4);
#pragma unroll
        for (int q = 0; q < 4; ++q)
            acc[q] += ((float)v0[q] + (float)v1[q]) + ((float)v2[q] + (float)v3[q]);
    }
    for (; e < end; ++e) {
        bf16x4 v = *reinterpret_cast<const bf16x4*>(z2b + (size_t)csr_src[e] * 48 + j * 4);
#pragma unroll
        for (int q = 0; q < 4; ++q) acc[q] += (float)v[q];
    }
    float inv = invdeg[node];
#pragma unroll
    for (int q = 0; q < 4; ++q) {
        int col = j * 4 + q;
        if (col < NCLS)
            out[(size_t)node * NCLS + col] += acc[q] * inv;
    }
}

extern "C" void kernel_launch(void* const* d_in, const int* in_sizes, int n_in,
                              void* d_out, int out_size, void* d_ws, size_t ws_size,
                              hipStream_t stream)
{
    const float* x   = (const float*)d_in[0];
    const int*   src = (const int*)  d_in[1];
    const int*   dst = (const int*)  d_in[2];
    const float* Ws1 = (const float*)d_in[3];
    const float* Wn1 = (const float*)d_in[4];
    const float* b1  = (const float*)d_in[5];
    const float* Ws2 = (const float*)d_in[6];
    const float* Wn2 = (const float*)d_in[7];
    const float* b2  = (const float*)d_in[8];
    float* out = (float*)d_out;

    // ---- workspace layout (int-slot / float-slot units) ----
    int*      wsi     = (int*)d_ws;
    int*      row_ptr = wsi;                 //  50,001
    int*      gcnt    = wsi + 50008;         //     196
    int*      gbase   = wsi + 50208;         //     197
    int*      gcur    = wsi + 50408;         //     196
    uint32_t* ebin    = (uint32_t*)(wsi + 50608);    // 800,000 u32
    uint16_t* csr_src = (uint16_t*)(wsi + 850608);   // 800,000 u16
    float*    wsf     = (float*)d_ws;
    float*    invdeg  = wsf + 1300000;               //  50,000 f32
    __bf16*   xb      = (__bf16*)(wsf + 1350000);    //  5.0M bf16
    uint32_t* mask    = (uint32_t*)(wsf + 4250000);  //  400K u32
    __bf16*   w1t     = (__bf16*)(wsf + 4650000);    // 57,344 bf16
    __bf16*   w2t     = (__bf16*)(wsf + 4680000);    // 24,576 bf16
    __bf16*   z2b     = (__bf16*)(wsf + 4700000);    //  2.4M bf16  (~23.6 MB)

    prep<<<PREP_NB, 256, 0, stream>>>(mask, x, xb, Ws1, Wn1, w1t, Ws2, Wn2, w2t, gcnt);

    bkt_hist <<<NBKT, 256, 0, stream>>>(dst, gcnt);
    bkt_scan <<<1, 256, 0, stream>>>(gcnt, gbase, gcur);
    bkt_bin  <<<NBKT, 256, 0, stream>>>(src, dst, gcur, ebin);
    bkt_build<<<NBKT, 256, 0, stream>>>(gbase, ebin, row_ptr, invdeg, csr_src);

    sage_fused<<<NODE_NB, 256, 0, stream>>>(
        row_ptr, csr_src, xb, invdeg, w1t, b1, mask, w2t, b2, out, z2b);
    agg2_bf<<<(N_NODES * 16 + 255) / 256, 256, 0, stream>>>(row_ptr, csr_src, z2b, invdeg, out);
}